// Round 7
// baseline (182.205 us; speedup 1.0000x reference)
//
#include <hip/hip_runtime.h>
#include <hip/hip_bf16.h>
#include <math.h>

#define BDIM 8
#define NPTS 2048
#define KNN 20
#define NCH 64
#define EPSV 1e-6f
#define CPAD 64

// 1-instruction cross-lane xor swizzle (BitMode: offset=(xor<<10)|0x1F), xor<=16
#define SWZ(v, code) __uint_as_float(__builtin_amdgcn_ds_swizzle(__float_as_uint(v), (code)))

// ---------------------------------------------------------------------------
// Prologue: squared norms xx[b][m] (16384 values) into d_ws.
// ---------------------------------------------------------------------------
__global__ __launch_bounds__(256) void xx_kernel(const float* __restrict__ y,
                                                 float* __restrict__ xx) {
    const int t = blockIdx.x * 256 + threadIdx.x;
    const int b = t >> 11, m = t & (NPTS - 1);
    const float* yb = y + (size_t)b * 3 * NPTS;
    const float a = yb[m], c = yb[NPTS + m], d = yb[2 * NPTS + m];
    xx[t] = a * a + c * c + d * d;
}

// ---------------------------------------------------------------------------
// Fused kernel: exact 20-NN + VN-linear/leaky + channel-equi normalize +
// head attention. One wave per point (b,n); lane = channel (vn phase).
// Barrier-free (wave-private LDS). Target: 64 VGPR -> 8 waves/SIMD.
// ---------------------------------------------------------------------------
__global__ __launch_bounds__(256, 8) void fused_kernel(
    const float* __restrict__ x, const float* __restrict__ y,
    const float* __restrict__ Wf1, const float* __restrict__ Wd1,
    const float* __restrict__ Wf2, const float* __restrict__ Wd2,
    const float* __restrict__ xx, float* __restrict__ out) {
    __shared__ uint2 cand[4][CPAD];       // sentinel-padded candidates
    __shared__ float4 gram[4][KNN][2];    // {ee,ey,ex,_},{e0,e1,e2,_}

    const int wave = threadIdx.x >> 6;
    const int lane = threadIdx.x & 63;
    // XCD-bijective swizzle: 512 n-groups, 8 XCDs -> XCD k owns groups
    // [k*64,(k+1)*64): consecutive groups share an XCD -> L2 merges the
    // partial 64B lines of the n-strided output.
    const int g = (blockIdx.x & 7) * 64 + (blockIdx.x >> 3);
    const int n = g * 4 + wave;
    const int b = blockIdx.y;
    const float* yb = y + (size_t)b * 3 * NPTS;
    const float* xxb = xx + (size_t)b * NPTS;

    const float yn0 = yb[n], yn1 = yb[NPTS + n], yn2 = yb[2 * NPTS + n];
    const float y20 = 2.0f * yn0, y21 = 2.0f * yn1, y22 = 2.0f * yn2;
    const float xxn = yn0 * yn0 + yn1 * yn1 + yn2 * yn2;

    // ---- q_x (independent chain, overlaps load stalls) -------------------
    const int c = lane;
    const float x0 = x[((size_t)b * 3 + 0) * NPTS + n];
    const float x1 = x[((size_t)b * 3 + 1) * NPTS + n];
    const float x2 = x[((size_t)b * 3 + 2) * NPTS + n];
    const float xq = x0 * x0 + x1 * x1 + x2 * x2;
    const float f = Wf1[c], gg = Wd1[c];
    const float dot1 = f * gg * xq;
    const float d21 = gg * gg * xq;
    const float coef1 = dot1 * __builtin_amdgcn_rcpf(d21 + EPSV);
    const float s_neg = f - coef1 * gg;
    const float sxc = 0.2f * f + 0.8f * ((dot1 >= 0.0f) ? f : s_neg);
    const float qn2 = sxc * sxc * xq;
    float totq = qn2;
    totq += SWZ(totq, 0x041F);
    totq += SWZ(totq, 0x081F);
    totq += SWZ(totq, 0x101F);
    totq += SWZ(totq, 0x201F);
    totq += SWZ(totq, 0x401F);
    totq += __shfl_xor(totq, 32);
    const float qn = sqrtf(qn2);
    const float qscale = (1.0f / fmaxf(qn, 1e-12f)) * (qn / fmaxf(sqrtf(totq), 1e-12f));
    const float qs = sxc * qscale;

    // sentinel-init candidate slots (before compaction writes; same-wave
    // LDS ops retire in program order)
    cand[wave][lane] = make_uint2(0xFF800000u /*-inf*/, 0x7fffffffu);

    // ======================= KNN phase =====================================
    // dist'[m] = 2<yn,ym> - |ym|^2   (drop -xxn: constant per row, order-inv)
    const int base_m = lane * 32;
    const float4* r0 = (const float4*)(yb + base_m);
    const float4* r1 = (const float4*)(yb + NPTS + base_m);
    const float4* r2 = (const float4*)(yb + 2 * NPTS + base_m);
    const float4* rx = (const float4*)(xxb + base_m);

    float dist[32];
    float t0a = -INFINITY, t1a = -INFINITY;  // top-2 of first half
    float t0b = -INFINITY, t1b = -INFINITY;  // top-2 of second half
#pragma unroll
    for (int q = 0; q < 8; ++q) {
        const float4 a0 = r0[q], a1 = r1[q], a2 = r2[q], ax = rx[q];
#define DCOMP(t, c0, c1, c2, xm, T0, T1)                                   \
        {                                                                  \
            const float d = fmaf(y20, (c0),                                \
                            fmaf(y21, (c1), fmaf(y22, (c2), -(xm))));      \
            dist[q * 4 + t] = d;                                           \
            const float hi = fmaxf(T0, d), lo = fminf(T0, d);              \
            T0 = hi;                                                       \
            T1 = fmaxf(T1, lo);                                            \
        }
        if (q < 4) {
            DCOMP(0, a0.x, a1.x, a2.x, ax.x, t0a, t1a)
            DCOMP(1, a0.y, a1.y, a2.y, ax.y, t0a, t1a)
            DCOMP(2, a0.z, a1.z, a2.z, ax.z, t0a, t1a)
            DCOMP(3, a0.w, a1.w, a2.w, ax.w, t0a, t1a)
        } else {
            DCOMP(0, a0.x, a1.x, a2.x, ax.x, t0b, t1b)
            DCOMP(1, a0.y, a1.y, a2.y, ax.y, t0b, t1b)
            DCOMP(2, a0.z, a1.z, a2.z, ax.z, t0b, t1b)
            DCOMP(3, a0.w, a1.w, a2.w, ax.w, t0b, t1b)
        }
#undef DCOMP
    }
    // merge two top-2s -> overall second max t1
    const float t1m = fmaxf(fminf(t0a, t0b), fmaxf(t1a, t1b));

    // bitonic sort (descending) of the 64 second-maxima; tau = 10th largest.
    // >=10 lanes have top2 >= tau, each contributing >=2 values >= tau.
    float key = t1m;
#pragma unroll
    for (int size = 2; size <= 64; size <<= 1) {
#pragma unroll
        for (int stride = size >> 1; stride > 0; stride >>= 1) {
            const float other = __shfl_xor(key, stride);
            const bool low = (lane & stride) == 0;
            const bool up = (lane & size) == 0;
            key = (low == up) ? fmaxf(key, other) : fminf(key, other);
        }
    }
    const float tau = __shfl(key, 9);

    // compact candidates >= tau (conditional writes; ballot+mbcnt slots)
    int wbase = 0;
#pragma unroll
    for (int j = 0; j < 32; ++j) {
        const bool pred = dist[j] >= tau;
        const unsigned long long bal = __ballot(pred);
        const int off = (int)__builtin_amdgcn_mbcnt_hi(
            (unsigned)(bal >> 32),
            __builtin_amdgcn_mbcnt_lo((unsigned)bal, 0u));
        const int slot = wbase + off;
        if (pred && slot < CPAD)
            cand[wave][slot] = make_uint2(__float_as_uint(dist[j]),
                                          (unsigned)(base_m + j));
        wbase += (int)__popcll(bal);
    }
    const int C = wbase;  // wave-uniform

    int myrank = KNN, mym = 0;
    if (C <= CPAD) {
        // exact top-20 by rank counting; compile-time-bounded unrolled
        // broadcast reads (sentinels rank last; C>=20 guaranteed).
        const uint2 e = cand[wave][lane];
        const float v = __uint_as_float(e.x);
        const int mm = (int)e.y;
        int rank = 0;
#pragma unroll
        for (int s = 0; s < CPAD; ++s) {
            const uint2 o = cand[wave][s];
            const float ov = __uint_as_float(o.x);
            rank += (ov > v || (ov == v && (int)o.y < mm)) ? 1 : 0;
        }
        myrank = rank;
        mym = mm;
    } else {
        // exact fallback (never taken with random data): 20 iterative pops
        int my_sel = 0;
        for (int i = 0; i < KNN; ++i) {
            float bv = dist[0];
            int bj = 0;
#pragma unroll
            for (int j = 1; j < 32; ++j)
                if (dist[j] > bv) { bv = dist[j]; bj = j; }
            int bm = base_m + bj;
            for (int off = 32; off > 0; off >>= 1) {
                const float ov = __shfl_xor(bv, off);
                const int om = __shfl_xor(bm, off);
                if (ov > bv || (ov == bv && om < bm)) { bv = ov; bm = om; }
            }
            if ((bm >> 5) == lane) {
                const int jw = bm & 31;
#pragma unroll
                for (int jj = 0; jj < 32; ++jj)
                    if (jj == jw) dist[jj] = -INFINITY;
            }
            if (lane == i) my_sel = bm;
        }
        myrank = lane;  // lanes >= 20 excluded below
        mym = my_sel;
    }

    // winners stage Gram values directly (scattered ~20 lanes active)
    if (myrank < KNN) {
        const float e0 = yb[mym] - yn0;
        const float e1 = yb[NPTS + mym] - yn1;
        const float e2 = yb[2 * NPTS + mym] - yn2;
        gram[wave][myrank][0] = make_float4(e0 * e0 + e1 * e1 + e2 * e2,
                                            e0 * yn0 + e1 * yn1 + e2 * yn2,
                                            e0 * x0 + e1 * x1 + e2 * x2, 0.0f);
        gram[wave][myrank][1] = make_float4(e0, e1, e2, 0.0f);
    }

    // ======================= VN-attention phase ============================
    const float yy = xxn;
    const float yx = yn0 * x0 + yn1 * x1 + yn2 * x2;

    const float wf0 = Wf2[2 * c], wf1v = Wf2[2 * c + 1];
    const float wd0 = Wd2[2 * c], wd1v = Wd2[2 * c + 1];
    const float cA = wf0 * wd0, cB = wf0 * wd1v + wf1v * wd0, cC = wf1v * wd1v;
    const float dA = wd0 * wd0, dB = 2.0f * wd0 * wd1v, dC = wd1v * wd1v;

    float t2[KNN], hh[KNN];
#pragma unroll
    for (int k = 0; k < KNN; ++k) {
        const float4 gv = gram[wave][k][0];
        const float ee = gv.x, ey = gv.y, ex = gv.z;
        const float dt = cA * ee + cB * ey + cC * yy;
        const float dd = dA * ee + dB * ey + dC * yy;
        const float cf = dt * __builtin_amdgcn_rcpf(dd + EPSV);
        const float uu = (dt < 0.0f) ? 0.8f * cf : 0.0f;
        const float a = wf0 - uu * wd0;
        const float bb = wf1v - uu * wd1v;
        t2[k] = a * (a * ee + bb * ey) + bb * (a * ey + bb * yy);  // |v|^2
        hh[k] = qs * (a * ex + bb * yx);                           // <v, qx>
    }

    // batched butterfly reductions (independent chains -> pipelined)
#pragma unroll
    for (int k = 0; k < KNN; ++k) t2[k] += SWZ(t2[k], 0x041F);
#pragma unroll
    for (int k = 0; k < KNN; ++k) t2[k] += SWZ(t2[k], 0x081F);
#pragma unroll
    for (int k = 0; k < KNN; ++k) t2[k] += SWZ(t2[k], 0x101F);
#pragma unroll
    for (int k = 0; k < KNN; ++k) t2[k] += SWZ(t2[k], 0x201F);
#pragma unroll
    for (int k = 0; k < KNN; ++k) t2[k] += SWZ(t2[k], 0x401F);
#pragma unroll
    for (int k = 0; k < KNN; ++k) t2[k] += __shfl_xor(t2[k], 32);
    // head (16-lane) sums of <v,qx>
#pragma unroll
    for (int k = 0; k < KNN; ++k) hh[k] += SWZ(hh[k], 0x041F);
#pragma unroll
    for (int k = 0; k < KNN; ++k) hh[k] += SWZ(hh[k], 0x081F);
#pragma unroll
    for (int k = 0; k < KNN; ++k) hh[k] += SWZ(hh[k], 0x101F);
#pragma unroll
    for (int k = 0; k < KNN; ++k) hh[k] += SWZ(hh[k], 0x201F);

    // single-pass softmax (no max-sub: |logit| <= 0.1443 provably) + output.
    // uu recomputed from LDS-resident gram to avoid u[20]/att[20] arrays.
    float lsum = 0.0f, o0 = 0.0f, o1 = 0.0f, o2 = 0.0f, bs = 0.0f;
#pragma unroll
    for (int k = 0; k < KNN; ++k) {
        const float4 gv = gram[wave][k][0];
        const float4 ev = gram[wave][k][1];
        const float rs = __builtin_amdgcn_rsqf(fmaxf(t2[k], 1e-24f));
        const float s = hh[k] * rs * 0.14433756729740643f;  // 1/sqrt(3*16)
        const float p = __expf(s);
        const float ee = gv.x, ey = gv.y;
        const float dt = cA * ee + cB * ey + cC * yy;
        const float dd = dA * ee + dB * ey + dC * yy;
        const float cf = dt * __builtin_amdgcn_rcpf(dd + EPSV);
        const float uu = (dt < 0.0f) ? 0.8f * cf : 0.0f;
        const float a = wf0 - uu * wd0;
        const float bb = wf1v - uu * wd1v;
        const float pa = p * a;
        lsum += p;
        bs += p * bb;
        o0 += pa * ev.x;
        o1 += pa * ev.y;
        o2 += pa * ev.z;
    }
    const float inv = __builtin_amdgcn_rcpf(lsum);

    float* ob = out + (((size_t)b * NCH + c) * 3) * NPTS + n;
    ob[0] = (o0 + bs * yn0) * inv;
    ob[NPTS] = (o1 + bs * yn1) * inv;
    ob[2 * NPTS] = (o2 + bs * yn2) * inv;
}

extern "C" void kernel_launch(void* const* d_in, const int* in_sizes, int n_in,
                              void* d_out, int out_size, void* d_ws, size_t ws_size,
                              hipStream_t stream) {
    const float* x = (const float*)d_in[0];
    const float* y = (const float*)d_in[1];
    const float* Wf1 = (const float*)d_in[2];
    const float* Wd1 = (const float*)d_in[3];
    const float* Wf2 = (const float*)d_in[4];
    const float* Wd2 = (const float*)d_in[5];
    float* out = (float*)d_out;
    float* xx = (float*)d_ws;  // B*N floats = 64 KB

    xx_kernel<<<dim3(BDIM * NPTS / 256), 256, 0, stream>>>(y, xx);
    dim3 grid(NPTS / 4, BDIM);
    fused_kernel<<<grid, 256, 0, stream>>>(x, y, Wf1, Wd1, Wf2, Wd2, xx, out);
}

// Round 11
// 150.596 us; speedup vs baseline: 1.2099x; 1.2099x over previous
//
#include <hip/hip_runtime.h>
#include <hip/hip_bf16.h>
#include <math.h>

#define BDIM 8
#define NPTS 2048
#define KNN 20
#define NCH 64
#define EPSV 1e-6f
#define CPAD 64
#define KC 10  // VN-phase chunk size (2 chunks of 10)

// 1-instruction cross-lane xor swizzle (BitMode: offset=(xor<<10)|0x1F), xor<=16
#define SWZ(v, code) __uint_as_float(__builtin_amdgcn_ds_swizzle(__float_as_uint(v), (code)))

// ---------------------------------------------------------------------------
// Prologue: squared norms xx[b][m] (16384 values) into d_ws.
// ---------------------------------------------------------------------------
__global__ __launch_bounds__(256) void xx_kernel(const float* __restrict__ y,
                                                 float* __restrict__ xx) {
    const int t = blockIdx.x * 256 + threadIdx.x;
    const int b = t >> 11, m = t & (NPTS - 1);
    const float* yb = y + (size_t)b * 3 * NPTS;
    const float a = yb[m], c = yb[NPTS + m], d = yb[2 * NPTS + m];
    xx[t] = a * a + c * c + d * d;
}

// ---------------------------------------------------------------------------
// Fused kernel: exact 20-NN + VN-linear/leaky + channel-equi normalize +
// head attention. One wave per point (b,n); lane = channel (vn phase).
// Barrier-free (wave-private LDS). No forced occupancy: avoid spills.
// ---------------------------------------------------------------------------
__global__ __launch_bounds__(256) void fused_kernel(
    const float* __restrict__ x, const float* __restrict__ y,
    const float* __restrict__ Wf1, const float* __restrict__ Wd1,
    const float* __restrict__ Wf2, const float* __restrict__ Wd2,
    const float* __restrict__ xx, float* __restrict__ out) {
    __shared__ uint2 cand[4][CPAD];       // sentinel-padded candidates
    __shared__ float4 gram[4][KNN][2];    // {ee,ey,ex,_},{e0,e1,e2,_}

    const int wave = threadIdx.x >> 6;
    const int lane = threadIdx.x & 63;
    // XCD-bijective swizzle: XCD k (bid%8) owns consecutive g in [k*64,k*64+64)
    // -> neighboring n-groups share an XCD L2 -> output lines merge.
    const int g = (blockIdx.x & 7) * 64 + (blockIdx.x >> 3);
    const int n = g * 4 + wave;
    const int b = blockIdx.y;
    const float* yb = y + (size_t)b * 3 * NPTS;
    const float* xxb = xx + (size_t)b * NPTS;

    const float yn0 = yb[n], yn1 = yb[NPTS + n], yn2 = yb[2 * NPTS + n];
    const float y20 = 2.0f * yn0, y21 = 2.0f * yn1, y22 = 2.0f * yn2;
    const float xxn = yn0 * yn0 + yn1 * yn1 + yn2 * yn2;

    // ---- q_x (independent chain, overlaps load stalls) -------------------
    const int c = lane;
    const float x0 = x[((size_t)b * 3 + 0) * NPTS + n];
    const float x1 = x[((size_t)b * 3 + 1) * NPTS + n];
    const float x2 = x[((size_t)b * 3 + 2) * NPTS + n];
    const float xq = x0 * x0 + x1 * x1 + x2 * x2;
    const float f = Wf1[c], gg = Wd1[c];
    const float dot1 = f * gg * xq;
    const float d21 = gg * gg * xq;
    const float coef1 = dot1 * __builtin_amdgcn_rcpf(d21 + EPSV);
    const float s_neg = f - coef1 * gg;
    const float sxc = 0.2f * f + 0.8f * ((dot1 >= 0.0f) ? f : s_neg);
    const float qn2 = sxc * sxc * xq;
    float totq = qn2;
    totq += SWZ(totq, 0x041F);
    totq += SWZ(totq, 0x081F);
    totq += SWZ(totq, 0x101F);
    totq += SWZ(totq, 0x201F);
    totq += SWZ(totq, 0x401F);
    totq += __shfl_xor(totq, 32);
    const float qn = sqrtf(qn2);
    const float qscale = (1.0f / fmaxf(qn, 1e-12f)) * (qn / fmaxf(sqrtf(totq), 1e-12f));
    const float qs = sxc * qscale;

    // sentinel-init candidate slots (same-wave LDS ops retire in order)
    cand[wave][lane] = make_uint2(0xFF800000u /*-inf*/, 0x7fffffffu);

    // ======================= KNN phase =====================================
    // dist'[m] = 2<yn,ym> - |ym|^2   (drop -xxn: constant per row, order-inv)
    const int base_m = lane * 32;
    const float4* r0 = (const float4*)(yb + base_m);
    const float4* r1 = (const float4*)(yb + NPTS + base_m);
    const float4* r2 = (const float4*)(yb + 2 * NPTS + base_m);
    const float4* rx = (const float4*)(xxb + base_m);

    float dist[32];
    float t0a = -INFINITY, t1a = -INFINITY;  // top-2 of first half
    float t0b = -INFINITY, t1b = -INFINITY;  // top-2 of second half
#pragma unroll
    for (int q = 0; q < 8; ++q) {
        const float4 a0 = r0[q], a1 = r1[q], a2 = r2[q], ax = rx[q];
#define DCOMP(t, c0, c1, c2, xm, T0, T1)                                   \
        {                                                                  \
            const float d = fmaf(y20, (c0),                                \
                            fmaf(y21, (c1), fmaf(y22, (c2), -(xm))));      \
            dist[q * 4 + t] = d;                                           \
            const float hi = fmaxf(T0, d), lo = fminf(T0, d);              \
            T0 = hi;                                                       \
            T1 = fmaxf(T1, lo);                                            \
        }
        if (q < 4) {
            DCOMP(0, a0.x, a1.x, a2.x, ax.x, t0a, t1a)
            DCOMP(1, a0.y, a1.y, a2.y, ax.y, t0a, t1a)
            DCOMP(2, a0.z, a1.z, a2.z, ax.z, t0a, t1a)
            DCOMP(3, a0.w, a1.w, a2.w, ax.w, t0a, t1a)
        } else {
            DCOMP(0, a0.x, a1.x, a2.x, ax.x, t0b, t1b)
            DCOMP(1, a0.y, a1.y, a2.y, ax.y, t0b, t1b)
            DCOMP(2, a0.z, a1.z, a2.z, ax.z, t0b, t1b)
            DCOMP(3, a0.w, a1.w, a2.w, ax.w, t0b, t1b)
        }
#undef DCOMP
    }
    // merge two top-2s -> overall second max
    const float t1m = fmaxf(fminf(t0a, t0b), fmaxf(t1a, t1b));

    // bitonic sort (descending) of the 64 second-maxima; tau = 10th largest.
    // >=10 lanes have top2 >= tau, each contributing >=2 values >= tau => C>=20.
    float key = t1m;
#pragma unroll
    for (int size = 2; size <= 64; size <<= 1) {
#pragma unroll
        for (int stride = size >> 1; stride > 0; stride >>= 1) {
            const float other = __shfl_xor(key, stride);
            const bool low = (lane & stride) == 0;
            const bool up = (lane & size) == 0;
            key = (low == up) ? fmaxf(key, other) : fminf(key, other);
        }
    }
    const float tau = __shfl(key, 9);

    // mark + per-lane count, prefix-scan for slots
    unsigned cmask = 0u;
    int lc = 0;
#pragma unroll
    for (int j = 0; j < 32; ++j)
        if (dist[j] >= tau) { cmask |= (1u << j); ++lc; }
    int incl = lc;
#pragma unroll
    for (int off = 1; off < 64; off <<= 1) {
        const int t = __shfl_up(incl, off);
        if (lane >= off) incl += t;
    }
    int slot = incl - lc;
    const int C = __shfl(incl, 63);  // wave-uniform

    // compact (conditional writes, statically unrolled)
#pragma unroll
    for (int j = 0; j < 32; ++j) {
        if (cmask & (1u << j)) {
            if (slot < CPAD)
                cand[wave][slot] = make_uint2(__float_as_uint(dist[j]),
                                              (unsigned)(base_m + j));
            ++slot;
        }
    }

    int mym = 0;
    bool winner;
    if (C <= CPAD) {
        // register bitonic sort of 64 packed keys: lane t = t-th largest dist
        const uint2 e = cand[wave][lane];
        unsigned uv = e.x;
        uv = (uv & 0x80000000u) ? ~uv : (uv | 0x80000000u);  // order-preserving
        unsigned long long kk =
            ((unsigned long long)(~uv) << 32) | (unsigned long long)e.y;
        if (lane >= C) kk = ~0ULL;
#pragma unroll
        for (int size = 2; size <= 64; size <<= 1) {
#pragma unroll
            for (int stride = size >> 1; stride > 0; stride >>= 1) {
                const unsigned long long o = __shfl_xor(kk, stride);
                const bool low = (lane & stride) == 0;
                const bool up = (lane & size) == 0;
                kk = (low == up) ? (kk < o ? kk : o) : (kk > o ? kk : o);
            }
        }
        mym = (int)(kk & 0xffffffffu);
        winner = (lane < KNN);
    } else {
        // exact fallback (never taken with random data): 20 iterative pops
        int my_sel = 0;
        for (int i = 0; i < KNN; ++i) {
            float bv = dist[0];
            int bj = 0;
#pragma unroll
            for (int j = 1; j < 32; ++j)
                if (dist[j] > bv) { bv = dist[j]; bj = j; }
            int bm = base_m + bj;
            for (int off = 32; off > 0; off >>= 1) {
                const float ov = __shfl_xor(bv, off);
                const int om = __shfl_xor(bm, off);
                if (ov > bv || (ov == bv && om < bm)) { bv = ov; bm = om; }
            }
            if ((bm >> 5) == lane) {
                const int jw = bm & 31;
#pragma unroll
                for (int jj = 0; jj < 32; ++jj)
                    if (jj == jw) dist[jj] = -INFINITY;
            }
            if (lane == i) my_sel = bm;
        }
        mym = my_sel;
        winner = (lane < KNN);
    }

    // winners (lanes 0..19, rank = lane) stage Gram values
    if (winner) {
        const float e0 = yb[mym] - yn0;
        const float e1 = yb[NPTS + mym] - yn1;
        const float e2 = yb[2 * NPTS + mym] - yn2;
        gram[wave][lane][0] = make_float4(e0 * e0 + e1 * e1 + e2 * e2,
                                          e0 * yn0 + e1 * yn1 + e2 * yn2,
                                          e0 * x0 + e1 * x1 + e2 * x2, 0.0f);
        gram[wave][lane][1] = make_float4(e0, e1, e2, 0.0f);
    }

    // ======================= VN-attention phase ============================
    const float yy = xxn;
    const float yx = yn0 * x0 + yn1 * x1 + yn2 * x2;

    const float wf0 = Wf2[2 * c], wf1v = Wf2[2 * c + 1];
    const float wd0 = Wd2[2 * c], wd1v = Wd2[2 * c + 1];
    const float cA = wf0 * wd0, cB = wf0 * wd1v + wf1v * wd0, cC = wf1v * wd1v;
    const float dA = wd0 * wd0, dB = 2.0f * wd0 * wd1v, dC = wd1v * wd1v;

    // no-max softmax accumulators (|logit| <= 0.58 provably; exp safe)
    float lsum = 0.0f, o0 = 0.0f, o1 = 0.0f, o2 = 0.0f, bs = 0.0f;

#pragma unroll
    for (int kc = 0; kc < KNN; kc += KC) {
        float t2[KC], hh[KC], u[KC];
#pragma unroll
        for (int kj = 0; kj < KC; ++kj) {
            const float4 gv = gram[wave][kc + kj][0];
            const float ee = gv.x, ey = gv.y, ex = gv.z;
            const float dt = cA * ee + cB * ey + cC * yy;
            const float dd = dA * ee + dB * ey + dC * yy;
            const float cf = dt * __builtin_amdgcn_rcpf(dd + EPSV);
            const float uu = (dt < 0.0f) ? 0.8f * cf : 0.0f;
            u[kj] = uu;
            const float a = wf0 - uu * wd0;
            const float bb = wf1v - uu * wd1v;
            t2[kj] = a * (a * ee + bb * ey) + bb * (a * ey + bb * yy);  // |v|^2
            hh[kj] = qs * (a * ex + bb * yx);                           // <v,qx>
        }

        // batched butterfly reductions (independent chains -> pipelined)
#pragma unroll
        for (int kj = 0; kj < KC; ++kj) t2[kj] += SWZ(t2[kj], 0x041F);
#pragma unroll
        for (int kj = 0; kj < KC; ++kj) t2[kj] += SWZ(t2[kj], 0x081F);
#pragma unroll
        for (int kj = 0; kj < KC; ++kj) t2[kj] += SWZ(t2[kj], 0x101F);
#pragma unroll
        for (int kj = 0; kj < KC; ++kj) t2[kj] += SWZ(t2[kj], 0x201F);
#pragma unroll
        for (int kj = 0; kj < KC; ++kj) t2[kj] += SWZ(t2[kj], 0x401F);
#pragma unroll
        for (int kj = 0; kj < KC; ++kj) t2[kj] += __shfl_xor(t2[kj], 32);
        // head (16-lane) sums of <v,qx>
#pragma unroll
        for (int kj = 0; kj < KC; ++kj) hh[kj] += SWZ(hh[kj], 0x041F);
#pragma unroll
        for (int kj = 0; kj < KC; ++kj) hh[kj] += SWZ(hh[kj], 0x081F);
#pragma unroll
        for (int kj = 0; kj < KC; ++kj) hh[kj] += SWZ(hh[kj], 0x101F);
#pragma unroll
        for (int kj = 0; kj < KC; ++kj) hh[kj] += SWZ(hh[kj], 0x201F);

        // logits + accumulate output
#pragma unroll
        for (int kj = 0; kj < KC; ++kj) {
            const float rs = __builtin_amdgcn_rsqf(fmaxf(t2[kj], 1e-24f));
            const float s = hh[kj] * rs * 0.14433756729740643f;  // 1/sqrt(48)
            const float p = __expf(s);
            const float a = wf0 - u[kj] * wd0;
            const float bb = wf1v - u[kj] * wd1v;
            const float4 ev = gram[wave][kc + kj][1];
            const float pa = p * a;
            lsum += p;
            bs += p * bb;
            o0 += pa * ev.x;
            o1 += pa * ev.y;
            o2 += pa * ev.z;
        }
    }
    const float inv = __builtin_amdgcn_rcpf(lsum);

    float* ob = out + (((size_t)b * NCH + c) * 3) * NPTS + n;
    ob[0] = (o0 + bs * yn0) * inv;
    ob[NPTS] = (o1 + bs * yn1) * inv;
    ob[2 * NPTS] = (o2 + bs * yn2) * inv;
}

extern "C" void kernel_launch(void* const* d_in, const int* in_sizes, int n_in,
                              void* d_out, int out_size, void* d_ws, size_t ws_size,
                              hipStream_t stream) {
    const float* x = (const float*)d_in[0];
    const float* y = (const float*)d_in[1];
    const float* Wf1 = (const float*)d_in[2];
    const float* Wd1 = (const float*)d_in[3];
    const float* Wf2 = (const float*)d_in[4];
    const float* Wd2 = (const float*)d_in[5];
    float* out = (float*)d_out;
    float* xx = (float*)d_ws;  // B*N floats = 64 KB

    xx_kernel<<<dim3(BDIM * NPTS / 256), 256, 0, stream>>>(y, xx);
    dim3 grid(NPTS / 4, BDIM);
    fused_kernel<<<grid, 256, 0, stream>>>(x, y, Wf1, Wd1, Wf2, Wd2, xx, out);
}